// Round 1
// baseline (267.061 us; speedup 1.0000x reference)
//
#include <hip/hip_runtime.h>

// SSL2d: per-channel sub-pixel bilinear shift with zero padding.
// x: (B=32, C=384, H=56, W=56) fp32; a,b: (C,) fp32 shifts in ~[-1,1]
// => floor(a), floor(b) in {-1, 0}: sampling touches only rows/cols +-1.
//
// v2: one thread = one 4(rows) x 4(cols, aligned) output tile.
//  - 5 source rows feed 4 output rows (streaming vertical lerp): issued
//    read ratio 1.25x vs 1.5x for the old 2x4 tile.
//  - XCD-chunked bijective block swizzle: vertically-adjacent tiles (which
//    share one source row) stay on the same XCD's L2, so the overlap row is
//    an L2 hit instead of a duplicate HBM fetch.
//  - all 5 row loads are independent (fully unrolled) -> latency hidden by
//    MLP; no LDS, no barriers.

constexpr int C  = 384;
constexpr int H  = 56;
constexpr int W  = 56;
constexpr int HW = H * W;     // 3136
constexpr int RQ = H / 4;     // 14 row-quads per plane
constexpr int QW = W / 4;     // 14 column-quads per row

__global__ __launch_bounds__(256) void ssl2d_kernel(
    const float* __restrict__ x,
    const float* __restrict__ a,
    const float* __restrict__ b,
    float* __restrict__ out,
    int total) {
    // Bijective XCD-chunked swizzle (m204 form): dispatch round-robins
    // blockIdx across the 8 XCDs; remap so each XCD owns a contiguous
    // chunk of the work -> row overlap between vertical neighbors and
    // whole planes stay in one XCD's L2.
    int nb  = (int)gridDim.x;
    int bid = (int)blockIdx.x;
    int qk  = nb >> 3, rr = nb & 7;
    int xcd = bid & 7, idx = bid >> 3;
    int sb  = (xcd < rr ? xcd * (qk + 1) : rr * (qk + 1) + (xcd - rr) * qk) + idx;

    int q = sb * 256 + (int)threadIdx.x;
    if (q >= total) return;

    // q -> (nc, hq, wq); consecutive lanes sweep wq then hq (coalesced).
    int t  = q / QW;
    int wq = q - t * QW;
    int nc = t / RQ;
    int hq = t - nc * RQ;
    int c  = nc % C;

    // Per-channel params (channel-uniform across ~196 consecutive threads).
    float ac  = a[c];
    float bc  = b[c];
    float iaf = floorf(ac);
    float ibf = floorf(bc);
    float fa  = ac - iaf;         // fractional shift along height
    float fb  = bc - ibf;         // fractional shift along width
    int   ia  = (int)iaf;         // in {-1, 0}
    int   ib  = (int)ibf;         // in {-1, 0}

    const float* plane = x + nc * HW;
    int wb = wq * 4;              // aligned output column base
    int h4 = hq * 4;              // output row base

    // Source cols needed: wb+ib .. wb+ib+4 (5 cols). The aligned float4 at wb
    // covers 4; one extra scalar at wb-1 (ib=-1) or wb+4 (ib=0).
    bool ib0    = (ib == 0);
    int  ecol   = ib0 ? (wb + 4) : (wb - 1);
    bool evalid = (unsigned)ecol < (unsigned)W;
    int  ecolc  = evalid ? ecol : 0;

    float fb1 = 1.0f - fb;
    float wa0 = 1.0f - fa;
    float wa1 = fa;
    int   R0  = h4 + ia;          // first source row (of 5)

    float p0 = 0.f, p1 = 0.f, p2 = 0.f, p3 = 0.f;   // prev row's h-lerp
    float* op = out + nc * HW + h4 * W + wb;

#pragma unroll
    for (int r = 0; r < 5; ++r) {
        int hy = R0 + r;
        bool vrow = (unsigned)hy < (unsigned)H;
        const float* rowp = plane + (vrow ? hy : 0) * W;
        float4 f = *(const float4*)(rowp + wb);     // aligned, coalesced
        float  e = rowp[ecolc];
        e = evalid ? e : 0.0f;
        float v0 = ib0 ? f.x : e;
        float v1 = ib0 ? f.y : f.x;
        float v2 = ib0 ? f.z : f.y;
        float v3 = ib0 ? f.w : f.z;
        float v4 = ib0 ? e   : f.w;
        float m = vrow ? 1.0f : 0.0f;               // zero-pad OOB rows
        float c0 = m * (fb1 * v0 + fb * v1);
        float c1 = m * (fb1 * v1 + fb * v2);
        float c2 = m * (fb1 * v2 + fb * v3);
        float c3 = m * (fb1 * v3 + fb * v4);
        if (r > 0) {
            float4 o;
            o.x = wa0 * p0 + wa1 * c0;
            o.y = wa0 * p1 + wa1 * c1;
            o.z = wa0 * p2 + wa1 * c2;
            o.w = wa0 * p3 + wa1 * c3;
            *(float4*)(op + (r - 1) * W) = o;
        }
        p0 = c0; p1 = c1; p2 = c2; p3 = c3;
    }
}

extern "C" void kernel_launch(void* const* d_in, const int* in_sizes, int n_in,
                              void* d_out, int out_size, void* d_ws, size_t ws_size,
                              hipStream_t stream) {
    const float* x = (const float*)d_in[0];
    const float* a = (const float*)d_in[1];
    const float* b = (const float*)d_in[2];
    float* out = (float*)d_out;

    int nplanes = out_size / HW;          // B*C = 12288
    int total = nplanes * RQ * QW;        // 2,408,448 tiles
    int blocks = (total + 255) / 256;     // 9,408 (tail-free)
    ssl2d_kernel<<<dim3(blocks), dim3(256), 0, stream>>>(x, a, b, out, total);
}